// Round 12
// baseline (133.719 us; speedup 1.0000x reference)
//
#include <hip/hip_runtime.h>
#include <math.h>
#include <float.h>

#define BATCH 64
#define Q 300
#define N 64
#define CLS 6
#define SLOTS 5   // ceil(300/64); slot 4 valid only for lane < 44
#define NT 256    // 4 waves
#define ARR_CAP 96

__device__ __forceinline__ int readlane_i(int x, int l) {
    return __builtin_amdgcn_readlane(x, l);
}
__device__ __forceinline__ float readlane_f(float x, int l) {
    return __int_as_float(__builtin_amdgcn_readlane(__float_as_int(x), l));
}
template <int CTRL>
__device__ __forceinline__ float fdpp(float x) {
    return __int_as_float(
        __builtin_amdgcn_update_dpp(0, __float_as_int(x), CTRL, 0xf, 0xf, true));
}
template <int CTRL>
__device__ __forceinline__ float fmin_dpp(float x) { return fminf(x, fdpp<CTRL>(x)); }
// full-wave min
__device__ __forceinline__ float wave_min(float x) {
    x = fmin_dpp<0xB1>(x);
    x = fmin_dpp<0x4E>(x);
    x = fmin_dpp<0x141>(x);
    x = fmin_dpp<0x140>(x);
    float r0 = readlane_f(x, 0),  r1 = readlane_f(x, 16),
          r2 = readlane_f(x, 32), r3 = readlane_f(x, 48);
    return fminf(fminf(r0, r1), fminf(r2, r3));
}
// fused two-smallest across the wave: input per-lane (lm1, lm2)
template <int CTRL>
__device__ __forceinline__ void min2_stage(float& m1, float& m2) {
    float p1 = fdpp<CTRL>(m1), p2 = fdpp<CTRL>(m2);
    float nm1 = fminf(m1, p1);
    float nm2 = fminf(fminf(m2, p2), fmaxf(m1, p1));
    m1 = nm1; m2 = nm2;
}
__device__ __forceinline__ void wave_min2(float lm1, float lm2, float& u1, float& u2) {
    float m1 = lm1, m2 = lm2;
    min2_stage<0xB1>(m1, m2);
    min2_stage<0x4E>(m1, m2);
    min2_stage<0x141>(m1, m2);
    min2_stage<0x140>(m1, m2);
    float a1 = readlane_f(m1, 0), b1 = readlane_f(m1, 16),
          c1 = readlane_f(m1, 32), d1 = readlane_f(m1, 48);
    float a2 = readlane_f(m2, 0), b2 = readlane_f(m2, 16),
          c2 = readlane_f(m2, 32), d2 = readlane_f(m2, 48);
    float l1 = fminf(a1, b1), h1 = fmaxf(a1, b1);
    float l2 = fminf(c1, d1), h2 = fmaxf(c1, d1);
    u1 = fminf(l1, l2);
    float sm1 = fminf(fmaxf(l1, l2), fminf(h1, h2));
    u2 = fminf(fminf(fminf(a2, b2), fminf(c2, d2)), sm1);
}

// One BLOCK (4 waves) per batch. Phase B (row reduction) parallel over waves.
// Phase C: Jacobi-parallel JV augmenting-row-reduction — each round up to 4
// free rows scanned concurrently (one per wave) against private register v
// (all copies synced via <=4 broadcast deltas/round); wave 0 commits the
// candidates with distinct columns (v only decreases => stale scans stay
// dual-feasible; taken edges tight since their column untouched this round);
// duplicates requeue, displaced owners re-enter the free mask. Free columns
// keep v=0 (rectangular-SAP invariant); SAP fallback for cap leftovers.
__global__ __launch_bounds__(NT, 1) void hml_fused_kernel(
    const float* __restrict__ exists,   // (B,Q,1)
    const float* __restrict__ coords,   // (B,Q,4)
    const float* __restrict__ width,    // (B,Q,1)
    const float* __restrict__ ef,       // (B,Q,6)
    const float* __restrict__ tracks,   // (B,N,6)
    float* __restrict__ part,           // (B,5) in d_ws
    unsigned int* __restrict__ counter, // 1 uint in d_ws (zeroed by memset)
    float* __restrict__ out)            // 6 floats
{
    const int b = blockIdx.x;
    const int tid = threadIdx.x;
    const int lane = tid & 63;
    const int wid = tid >> 6;
    const bool s4ok = (lane < (Q - 4 * 64));  // lane < 44
    const float INF = __builtin_inff();

    __shared__ float s_u[N];
    __shared__ int   s_want[N];
    __shared__ int s_colowner[SLOTS * 64];
    __shared__ int s_row4col[SLOTS * 64];
    __shared__ int s_matched[SLOTS * 64];
    __shared__ unsigned long long s_freemask;
    __shared__ int   s_cand_i[4], s_cand_j[4], s_cand_ok[4];
    __shared__ float s_cand_u1[4], s_cand_u2[4];
    __shared__ int   s_commit_col[4];
    __shared__ float s_commit_dv[4];

    // ---- stage column (pred) features into registers (every wave) ----
    float co0[SLOTS], co1[SLOTS], co2[SLOTS], co3[SLOTS];
    float wi_[SLOTS], pe_[SLOTS], ec2_[SLOTS];
    float base_[CLS][SLOTS];   // 2*(-lo_c) + ec2
    #pragma unroll
    for (int s = 0; s < SLOTS; ++s) {
        const int col = lane + 64 * s;
        const bool valid = (col < Q);
        const int idx = valid ? (b * Q + col) : (b * Q);  // clamp: benign addr
        float e = exists[idx];
        float pe = fminf(fmaxf(e, 1e-6f), 1.0f - 1e-6f);
        pe_[s] = pe;
        float e2 = -2.0f * logf(pe + 1e-8f);
        ec2_[s] = e2;
        wi_[s] = width[idx];
        const float4 c4 = reinterpret_cast<const float4*>(coords)[idx];
        co0[s] = c4.x; co1[s] = c4.y; co2[s] = c4.z; co3[s] = c4.w;
        const float* lp = ef + (size_t)idx * CLS;
        float x0 = lp[0], x1 = lp[1], x2 = lp[2], x3 = lp[3], x4 = lp[4], x5 = lp[5];
        float mx = fmaxf(fmaxf(fmaxf(x0, x1), fmaxf(x2, x3)), fmaxf(x4, x5));
        float sum = expf(x0 - mx) + expf(x1 - mx) + expf(x2 - mx)
                  + expf(x3 - mx) + expf(x4 - mx) + expf(x5 - mx);
        float off = mx + logf(sum);               // lo_c = x_c - off
        base_[0][s] = fmaf(-2.0f, x0 - off, e2);
        base_[1][s] = fmaf(-2.0f, x1 - off, e2);
        base_[2][s] = fmaf(-2.0f, x2 - off, e2);
        base_[3][s] = fmaf(-2.0f, x3 - off, e2);
        base_[4][s] = fmaf(-2.0f, x4 - off, e2);
        base_[5][s] = fmaf(-2.0f, x5 - off, e2);
    }

    // ---- row (GT) features: row = lane, every wave holds all 64 rows ----
    float g0r, g1r, g2r, g3r, g4r; int clsr;
    {
        const float* gp = tracks + ((size_t)b * N + lane) * 6;
        g0r = gp[0]; g1r = gp[1]; g2r = gp[2]; g3r = gp[3]; g4r = gp[4];
        clsr = (int)gp[5];
    }

    // private v copy per wave (kept identical across waves via round deltas)
    float v_[SLOTS];
    #pragma unroll
    for (int s = 0; s < SLOTS; ++s) v_[s] = 0.0f;

    // ---- Phase B (parallel over waves): u_i = min_j c[i][j] + argmin ----
    for (int t = 0; t < N / 4; ++t) {
        const int i = (N / 4) * wid + t;
        float g0 = readlane_f(g0r, i), g1 = readlane_f(g1r, i),
              g2 = readlane_f(g2r, i), g3 = readlane_f(g3r, i),
              g4 = readlane_f(g4r, i);
        int cls = readlane_i(clsr, i);
        float msk[SLOTS];
        #pragma unroll
        for (int s = 0; s < SLOTS; ++s) {
            const bool slotvalid = (s < SLOTS - 1) || s4ok;
            float t01 = (cls == 1) ? base_[1][s] : base_[0][s];
            float t23 = (cls == 3) ? base_[3][s] : base_[2][s];
            float t45 = (cls == 5) ? base_[5][s] : base_[4][s];
            float t03 = (cls >= 2) ? t23 : t01;
            float bb  = (cls >= 4) ? t45 : t03;
            float cc = fabsf(co0[s] - g0) + fabsf(co1[s] - g1)
                     + fabsf(co2[s] - g2) + fabsf(co3[s] - g3);
            float cost = fmaf(5.0f, cc, fmaf(2.0f, fabsf(wi_[s] - g4), bb));
            msk[s] = slotvalid ? cost : INF;
        }
        float lbest = fminf(fminf(fminf(msk[0], msk[1]), fminf(msk[2], msk[3])), msk[4]);
        unsigned jc = 0x7fffffffu;
        #pragma unroll
        for (int s = SLOTS - 1; s >= 0; --s)
            if (msk[s] == lbest) jc = (unsigned)(lane + 64 * s);
        float gmin = wave_min(lbest);
        unsigned long long ball = __ballot(lbest == gmin);
        int winner = __ffsll(ball) - 1;
        int bj = readlane_i((int)jc, winner);
        if (lane == 0) { s_u[i] = gmin; s_want[i] = bj; }
    }
    __syncthreads();

    // ---- conflict resolution (wave 0), builds row4col + freemask ----
    int col4row_r = -1;   // authoritative only on wave 0
    if (wid == 0) {
        int want_ = s_want[lane];
        #pragma unroll
        for (int s = 0; s < SLOTS; ++s) {
            s_colowner[lane + 64 * s] = 0x7fffffff;
            s_row4col[lane + 64 * s] = -1;
        }
        __threadfence_block();
        atomicMin(&s_colowner[want_], lane);
        __threadfence_block();
        col4row_r = (s_colowner[want_] == lane) ? want_ : -1;
        if (col4row_r >= 0) s_row4col[col4row_r] = lane;
        unsigned long long fb = __ballot(col4row_r == -1);
        if (lane == 0) s_freemask = fb;
    }
    __syncthreads();

    // ---- Phase C0: Jacobi-parallel augmenting row reduction (all waves) ----
    volatile unsigned long long* pfm = &s_freemask;
    int round = 0;
    for (;;) {
        unsigned long long fm = *pfm;
        if (fm == 0ull || round >= ARR_CAP) break;
        ++round;
        // wave w takes the w-th set bit (uniform per wave)
        unsigned long long m = fm;
        int myrow = -1;
        #pragma unroll
        for (int t = 0; t < 4; ++t) {
            int idx = m ? (__ffsll(m) - 1) : -1;
            if (t == wid) myrow = idx;
            m &= (m - 1);
        }
        if (myrow >= 0) {
            const int i = myrow;
            float g0 = readlane_f(g0r, i), g1 = readlane_f(g1r, i),
                  g2 = readlane_f(g2r, i), g3 = readlane_f(g3r, i),
                  g4 = readlane_f(g4r, i);
            int cls = readlane_i(clsr, i);
            float m1 = INF, m2 = INF;
            unsigned j1 = 0x7fffffffu;
            #pragma unroll
            for (int s = 0; s < SLOTS; ++s) {
                const bool slotvalid = (s < SLOTS - 1) || s4ok;
                float t01 = (cls == 1) ? base_[1][s] : base_[0][s];
                float t23 = (cls == 3) ? base_[3][s] : base_[2][s];
                float t45 = (cls == 5) ? base_[5][s] : base_[4][s];
                float t03 = (cls >= 2) ? t23 : t01;
                float bb  = (cls >= 4) ? t45 : t03;
                float cc = fabsf(co0[s] - g0) + fabsf(co1[s] - g1)
                         + fabsf(co2[s] - g2) + fabsf(co3[s] - g3);
                float cost = fmaf(5.0f, cc, fmaf(2.0f, fabsf(wi_[s] - g4), bb));
                float r = slotvalid ? (cost - v_[s]) : INF;
                if (r < m1)      { m2 = m1; m1 = r; j1 = (unsigned)(lane + 64 * s); }
                else if (r < m2) { m2 = r; }
            }
            float u1, u2;
            wave_min2(m1, m2, u1, u2);
            unsigned long long ball = __ballot(m1 == u1);
            int winner = __ffsll(ball) - 1;
            int bj = readlane_i((int)j1, winner);
            if (lane == 0) {
                s_cand_ok[wid] = 1;
                s_cand_i[wid] = i;
                s_cand_j[wid] = bj;
                s_cand_u1[wid] = u1;
                s_cand_u2[wid] = u2;
            }
        } else if (lane == 0) {
            s_cand_ok[wid] = 0;
        }
        __syncthreads();

        if (wid == 0) {
            int ok = 0, ii = -1, jj = -1, kk = -1;
            float uu1 = 0.0f, uu2 = 0.0f;
            if (lane < 4) {
                ok = s_cand_ok[lane];
                if (ok) {
                    ii = s_cand_i[lane]; jj = s_cand_j[lane];
                    uu1 = s_cand_u1[lane]; uu2 = s_cand_u2[lane];
                }
            }
            const int ok_orig = ok;
            // duplicate-column check vs earlier candidates (requeue losers)
            #pragma unroll
            for (int e = 0; e < 3; ++e) {
                int oe = readlane_i(ok_orig, e);
                int je = readlane_i(jj, e);
                if (lane < 4 && lane > e && ok && oe && je == jj) ok = 0;
            }
            if (lane < 4) {
                if (ok) {
                    kk = s_row4col[jj];        // pre-round owner (-1 if none)
                    s_row4col[jj] = ii;
                    s_u[ii] = uu2;
                    s_commit_col[lane] = jj;
                    s_commit_dv[lane] = uu2 - uu1;
                } else {
                    s_commit_col[lane] = -1;
                    s_commit_dv[lane] = 0.0f;
                }
            }
            // freemask + col4row updates (all 64 lanes of wave 0)
            unsigned long long fm2 = s_freemask;
            #pragma unroll
            for (int c = 0; c < 4; ++c) {
                int okc = readlane_i(ok, c);
                int ic  = readlane_i(ii, c);
                int jc  = readlane_i(jj, c);
                int kc  = readlane_i(kk, c);
                if (okc) {
                    fm2 &= ~(1ull << ic);
                    if (kc >= 0) fm2 |= (1ull << kc);
                    if (lane == ic) col4row_r = jc;
                    else if (lane == kc) col4row_r = -1;
                }
            }
            if (lane == 0) s_freemask = fm2;
        }
        __syncthreads();

        // apply committed v deltas to every wave's private copy
        #pragma unroll
        for (int c = 0; c < 4; ++c) {
            int col = s_commit_col[c];
            float dv = s_commit_dv[c];
            if (col >= 0 && (col & 63) == lane) {
                int cs = col >> 6;
                #pragma unroll
                for (int s = 0; s < SLOTS; ++s)
                    if (s == cs) v_[s] -= dv;
            }
        }
    }
    if (wid != 0) return;   // uniform loop exit; no barriers after this point

    // ================= wave 0 only from here =================
    float u_r = s_u[lane];

    // ---- Phase C1: shortest augmenting path for any cap leftovers ----
    float shortest_[SLOTS];
    int path_[SLOTS];
    bool SC_[SLOTS];

    unsigned long long freeball = __ballot(col4row_r == -1);
    while (freeball) {
        const int cur = __ffsll(freeball) - 1;
        freeball &= (freeball - 1);

        #pragma unroll
        for (int s = 0; s < SLOTS; ++s) {
            shortest_[s] = INF;
            SC_[s] = (s == SLOTS - 1) ? !s4ok : false;
        }
        bool SRr = false;
        float minv = 0.0f;
        int i = cur;
        int sink;

        for (;;) {
            SRr = SRr || (lane == i);
            float g0 = readlane_f(g0r, i), g1 = readlane_f(g1r, i),
                  g2 = readlane_f(g2r, i), g3 = readlane_f(g3r, i),
                  g4 = readlane_f(g4r, i);
            int   cls = readlane_i(clsr, i);
            float muv = minv - readlane_f(u_r, i);

            float bb[SLOTS];
            #pragma unroll
            for (int s = 0; s < SLOTS; ++s) {
                float t01 = (cls == 1) ? base_[1][s] : base_[0][s];
                float t23 = (cls == 3) ? base_[3][s] : base_[2][s];
                float t45 = (cls == 5) ? base_[5][s] : base_[4][s];
                float t03 = (cls >= 2) ? t23 : t01;
                bb[s] = (cls >= 4) ? t45 : t03;
            }
            float msk[SLOTS];
            #pragma unroll
            for (int s = 0; s < SLOTS; ++s) {
                if (!SC_[s]) {
                    float cc = fabsf(co0[s] - g0) + fabsf(co1[s] - g1)
                             + fabsf(co2[s] - g2) + fabsf(co3[s] - g3);
                    float cost = fmaf(5.0f, cc, fmaf(2.0f, fabsf(wi_[s] - g4), bb[s]));
                    float d = muv + cost - v_[s];
                    if (d < shortest_[s]) { shortest_[s] = d; path_[s] = i; }
                    msk[s] = shortest_[s];
                } else {
                    msk[s] = INF;
                }
            }
            float lbest = fminf(fminf(fminf(msk[0], msk[1]), fminf(msk[2], msk[3])), msk[4]);
            unsigned jc = 0x7fffffffu;
            #pragma unroll
            for (int s = SLOTS - 1; s >= 0; --s)
                if (msk[s] == lbest) jc = (unsigned)(lane + 64 * s);
            float gmin = wave_min(lbest);
            unsigned long long ball = __ballot(lbest == gmin);
            int winner = __ffsll(ball) - 1;
            int bj = readlane_i((int)jc, winner);
            minv = gmin;

            const int bl = bj & 63, bs = bj >> 6;
            #pragma unroll
            for (int s = 0; s < SLOTS; ++s)
                if (bs == s && lane == bl) SC_[s] = true;
            unsigned long long ball2 = __ballot(col4row_r == bj);
            if (ball2 == 0ull) { sink = bj; break; }
            i = __ffsll(ball2) - 1;
        }

        const float minval = minv;
        {
            int c = col4row_r;
            int cl = c & 63, cs = c >> 6;
            float t0 = __shfl(shortest_[0], cl), t1 = __shfl(shortest_[1], cl),
                  t2 = __shfl(shortest_[2], cl), t3 = __shfl(shortest_[3], cl),
                  t4 = __shfl(shortest_[4], cl);
            float shc = t0;
            shc = (cs == 1) ? t1 : shc;
            shc = (cs == 2) ? t2 : shc;
            shc = (cs == 3) ? t3 : shc;
            shc = (cs == 4) ? t4 : shc;
            if (lane == cur) u_r += minval;
            else if (SRr)    u_r += minval - shc;
        }
        #pragma unroll
        for (int s = 0; s < SLOTS; ++s) {
            const bool slotvalid = (s < SLOTS - 1) || s4ok;
            if (slotvalid && SC_[s]) v_[s] -= minval - shortest_[s];
        }
        int j = sink;
        for (;;) {
            const int jl = j & 63, js = j >> 6;
            int ii_sel = path_[0];
            ii_sel = (js == 1) ? path_[1] : ii_sel;
            ii_sel = (js == 2) ? path_[2] : ii_sel;
            ii_sel = (js == 3) ? path_[3] : ii_sel;
            ii_sel = (js == 4) ? path_[4] : ii_sel;
            int ii = readlane_i(ii_sel, jl);
            int t = readlane_i(col4row_r, ii);
            if (lane == ii) col4row_r = j;
            j = t;
            if (ii == cur) break;
        }
    }

    // ---- matched-column bitmap for the noobj term (wave-0 internal) ----
    #pragma unroll
    for (int s = 0; s < SLOTS; ++s) s_matched[lane + 64 * s] = 0;
    __threadfence_block();
    s_matched[col4row_r] = 1;
    __threadfence_block();

    // ---- per-batch loss partials ----
    float pc, pw, pef, pex;
    {
        const int p = col4row_r;
        const int pl = p & 63, ps = p >> 6;
        #define GATH(dst, a0, a1, a2, a3, a4)                                   \
        {   float t0 = __shfl(a0, pl), t1 = __shfl(a1, pl), t2 = __shfl(a2, pl),\
                  t3 = __shfl(a3, pl), t4 = __shfl(a4, pl);                     \
            dst = t0;                                                           \
            dst = (ps == 1) ? t1 : dst;                                         \
            dst = (ps == 2) ? t2 : dst;                                         \
            dst = (ps == 3) ? t3 : dst;                                         \
            dst = (ps == 4) ? t4 : dst; }
        float mc0, mc1, mc2, mc3, mw, mpe, me2;
        GATH(mc0, co0[0], co0[1], co0[2], co0[3], co0[4])
        GATH(mc1, co1[0], co1[1], co1[2], co1[3], co1[4])
        GATH(mc2, co2[0], co2[1], co2[2], co2[3], co2[4])
        GATH(mc3, co3[0], co3[1], co3[2], co3[3], co3[4])
        GATH(mw,  wi_[0], wi_[1], wi_[2], wi_[3], wi_[4])
        GATH(mpe, pe_[0], pe_[1], pe_[2], pe_[3], pe_[4])
        GATH(me2, ec2_[0], ec2_[1], ec2_[2], ec2_[3], ec2_[4])
        float b0, b1, b2, b3, b4, b5;
        GATH(b0, base_[0][0], base_[0][1], base_[0][2], base_[0][3], base_[0][4])
        GATH(b1, base_[1][0], base_[1][1], base_[1][2], base_[1][3], base_[1][4])
        GATH(b2, base_[2][0], base_[2][1], base_[2][2], base_[2][3], base_[2][4])
        GATH(b3, base_[3][0], base_[3][1], base_[3][2], base_[3][3], base_[3][4])
        GATH(b4, base_[4][0], base_[4][1], base_[4][2], base_[4][3], base_[4][4])
        GATH(b5, base_[5][0], base_[5][1], base_[5][2], base_[5][3], base_[5][4])
        #undef GATH
        float mb = b0;
        mb = (clsr == 1) ? b1 : mb;
        mb = (clsr == 2) ? b2 : mb;
        mb = (clsr == 3) ? b3 : mb;
        mb = (clsr == 4) ? b4 : mb;
        mb = (clsr == 5) ? b5 : mb;
        pc = fabsf(mc0 - g0r) + fabsf(mc1 - g1r) + fabsf(mc2 - g2r) + fabsf(mc3 - g3r);
        pw = fabsf(mw - g4r);
        pef = (mb - me2) * 0.5f;
        pex = -logf(mpe);
    }
    float pno = 0.0f;
    #pragma unroll
    for (int s = 0; s < SLOTS; ++s) {
        const bool slotvalid = (s < SLOTS - 1) || s4ok;
        if (slotvalid && !s_matched[lane + 64 * s]) pno -= logf(1.0f - pe_[s]);
    }

    // ---- wave reduce 5 partials; publish; last block finalizes ----
    float vals[5] = {pc, pw, pef, pex, pno};
    #pragma unroll
    for (int k = 0; k < 5; ++k) {
        float x = vals[k];
        #pragma unroll
        for (int off = 1; off < 64; off <<= 1) x += __shfl_xor(x, off);
        vals[k] = x;
    }
    if (lane == 0) {
        #pragma unroll
        for (int k = 0; k < 5; ++k) atomicExch(&part[b * 5 + k], vals[k]);
    }
    __threadfence();
    unsigned int done = 0;
    if (lane == 0) done = atomicAdd(counter, 1u);
    done = __shfl(done, 0);
    if (done == BATCH - 1) {
        __threadfence();
        float s0 = atomicAdd(&part[lane * 5 + 0], 0.0f);
        float s1 = atomicAdd(&part[lane * 5 + 1], 0.0f);
        float s2 = atomicAdd(&part[lane * 5 + 2], 0.0f);
        float s3 = atomicAdd(&part[lane * 5 + 3], 0.0f);
        float s4 = atomicAdd(&part[lane * 5 + 4], 0.0f);
        #pragma unroll
        for (int off = 1; off < 64; off <<= 1) {
            s0 += __shfl_xor(s0, off);
            s1 += __shfl_xor(s1, off);
            s2 += __shfl_xor(s2, off);
            s3 += __shfl_xor(s3, off);
            s4 += __shfl_xor(s4, off);
        }
        if (lane == 0) {
            const float n_matched = 4096.0f;     // B*N (mask all-ones)
            const float n_unmatched = 15104.0f;  // B*Q - B*N
            float coord = 5.0f * s0 / n_matched;
            float wloss = 2.0f * s1 / n_matched;
            float efl   = 2.0f * s2 / n_matched;
            float exl   = 2.0f * s3 / n_matched;
            float nol   = 1.0f * s4 / n_unmatched;
            out[0] = coord + wloss + efl + exl + nol;
            out[1] = coord;
            out[2] = wloss;
            out[3] = efl;
            out[4] = exl;
            out[5] = nol;
        }
    }
}

extern "C" void kernel_launch(void* const* d_in, const int* in_sizes, int n_in,
                              void* d_out, int out_size, void* d_ws, size_t ws_size,
                              hipStream_t stream) {
    const float* exists = (const float*)d_in[0];  // (64,300,1)
    const float* coords = (const float*)d_in[1];  // (64,300,4)
    const float* width  = (const float*)d_in[2];  // (64,300,1)
    const float* ef     = (const float*)d_in[3];  // (64,300,6)
    const float* tracks = (const float*)d_in[4];  // (64,64,6)
    // d_in[5] = track_mask: all ones by construction, unused

    float* part = (float*)d_ws;                                   // 64*5 floats
    unsigned int* counter = (unsigned int*)((char*)d_ws + BATCH * 5 * sizeof(float));
    (void)hipMemsetAsync(counter, 0, sizeof(unsigned int), stream);  // capture-legal

    hml_fused_kernel<<<BATCH, NT, 0, stream>>>(exists, coords, width, ef, tracks,
                                               part, counter, (float*)d_out);
}

// Round 13
// 119.769 us; speedup vs baseline: 1.1165x; 1.1165x over previous
//
#include <hip/hip_runtime.h>
#include <math.h>
#include <float.h>

#define BATCH 64
#define Q 300
#define N 64
#define CLS 6
#define SLOTS 5   // ceil(300/64); slot 4 valid only for lane < 44
#define NT 256    // 4 waves: Phase B split 16 rows/wave; Phase C on wave 0

__device__ __forceinline__ int readlane_i(int x, int l) {
    return __builtin_amdgcn_readlane(x, l);
}
__device__ __forceinline__ float readlane_f(float x, int l) {
    return __int_as_float(__builtin_amdgcn_readlane(__float_as_int(x), l));
}
template <int CTRL>
__device__ __forceinline__ float fdpp(float x) {
    return __int_as_float(
        __builtin_amdgcn_update_dpp(0, __float_as_int(x), CTRL, 0xf, 0xf, true));
}
template <int CTRL>
__device__ __forceinline__ float fmin_dpp(float x) { return fminf(x, fdpp<CTRL>(x)); }
// full-wave min via 4 DPP stages + 4 leader readlanes
__device__ __forceinline__ float wave_min(float x) {
    x = fmin_dpp<0xB1>(x);
    x = fmin_dpp<0x4E>(x);
    x = fmin_dpp<0x141>(x);
    x = fmin_dpp<0x140>(x);
    float r0 = readlane_f(x, 0),  r1 = readlane_f(x, 16),
          r2 = readlane_f(x, 32), r3 = readlane_f(x, 48);
    return fminf(fminf(r0, r1), fminf(r2, r3));
}
// fused two-smallest across the wave: per-lane (m1,m2) -> global (u1,u2).
// u2 = second smallest of the union {m1_l, m2_l}: equals JV's second-min
// (= min(winner's m2, other lanes' m1)) since any lane's m2 >= its m1.
template <int CTRL>
__device__ __forceinline__ void min2_stage(float& m1, float& m2) {
    float p1 = fdpp<CTRL>(m1), p2 = fdpp<CTRL>(m2);
    float nm1 = fminf(m1, p1);
    float nm2 = fminf(fminf(m2, p2), fmaxf(m1, p1));
    m1 = nm1; m2 = nm2;
}
__device__ __forceinline__ void wave_min2(float lm1, float lm2, float& u1, float& u2) {
    float m1 = lm1, m2 = lm2;
    min2_stage<0xB1>(m1, m2);
    min2_stage<0x4E>(m1, m2);
    min2_stage<0x141>(m1, m2);
    min2_stage<0x140>(m1, m2);
    float a1 = readlane_f(m1, 0), b1 = readlane_f(m1, 16),
          c1 = readlane_f(m1, 32), d1 = readlane_f(m1, 48);
    float a2 = readlane_f(m2, 0), b2 = readlane_f(m2, 16),
          c2 = readlane_f(m2, 32), d2 = readlane_f(m2, 48);
    float l1 = fminf(a1, b1), h1 = fmaxf(a1, b1);
    float l2 = fminf(c1, d1), h2 = fmaxf(c1, d1);
    u1 = fminf(l1, l2);
    float sm1 = fminf(fmaxf(l1, l2), fminf(h1, h2));
    u2 = fminf(fminf(fminf(a2, b2), fminf(c2, d2)), sm1);
}

// One BLOCK (4 waves) per batch; rows (GT) = lanes, columns (preds) = 5
// register slots per lane. Phase B (row reduction) parallel over 4 waves;
// wave 0 then: conflict resolution (lowest row wins argmin column) ->
// serial JV augmenting-row-reduction (u_i = u2, v[j1] -= (u2-u1), displace
// owner; v only decreases on matched columns so free columns keep v=0,
// preserving the rectangular-SAP invariant) with the fused wave_min2 chain
// (single reduction per iteration instead of R11's two) -> SAP fallback for
// cap leftovers -> loss epilogue. Cross-lane via readlane/DPP/ballot.
__global__ __launch_bounds__(NT, 1) void hml_fused_kernel(
    const float* __restrict__ exists,   // (B,Q,1)
    const float* __restrict__ coords,   // (B,Q,4)
    const float* __restrict__ width,    // (B,Q,1)
    const float* __restrict__ ef,       // (B,Q,6)
    const float* __restrict__ tracks,   // (B,N,6)
    float* __restrict__ part,           // (B,5) in d_ws
    unsigned int* __restrict__ counter, // 1 uint in d_ws (zeroed by memset)
    float* __restrict__ out)            // 6 floats
{
    const int b = blockIdx.x;
    const int tid = threadIdx.x;
    const int lane = tid & 63;
    const int wid = tid >> 6;
    const bool s4ok = (lane < (Q - 4 * 64));  // lane < 44
    const float INF = __builtin_inff();

    __shared__ float s_u[N];
    __shared__ int   s_want[N];
    __shared__ int s_colowner[SLOTS * 64];  // column -> lowest row wanting it
    __shared__ int s_matched[SLOTS * 64];   // column matched bitmap

    // ---- stage column (pred) features into registers (every wave) ----
    float co0[SLOTS], co1[SLOTS], co2[SLOTS], co3[SLOTS];
    float wi_[SLOTS], pe_[SLOTS], ec2_[SLOTS];
    float base_[CLS][SLOTS];   // 2*(-lo_c) + ec2
    #pragma unroll
    for (int s = 0; s < SLOTS; ++s) {
        const int col = lane + 64 * s;
        const bool valid = (col < Q);
        const int idx = valid ? (b * Q + col) : (b * Q);  // clamp: benign addr
        float e = exists[idx];
        float pe = fminf(fmaxf(e, 1e-6f), 1.0f - 1e-6f);
        pe_[s] = pe;
        float e2 = -2.0f * logf(pe + 1e-8f);
        ec2_[s] = e2;
        wi_[s] = width[idx];
        const float4 c4 = reinterpret_cast<const float4*>(coords)[idx];
        co0[s] = c4.x; co1[s] = c4.y; co2[s] = c4.z; co3[s] = c4.w;
        const float* lp = ef + (size_t)idx * CLS;
        float x0 = lp[0], x1 = lp[1], x2 = lp[2], x3 = lp[3], x4 = lp[4], x5 = lp[5];
        float mx = fmaxf(fmaxf(fmaxf(x0, x1), fmaxf(x2, x3)), fmaxf(x4, x5));
        float sum = expf(x0 - mx) + expf(x1 - mx) + expf(x2 - mx)
                  + expf(x3 - mx) + expf(x4 - mx) + expf(x5 - mx);
        float off = mx + logf(sum);               // lo_c = x_c - off
        base_[0][s] = fmaf(-2.0f, x0 - off, e2);
        base_[1][s] = fmaf(-2.0f, x1 - off, e2);
        base_[2][s] = fmaf(-2.0f, x2 - off, e2);
        base_[3][s] = fmaf(-2.0f, x3 - off, e2);
        base_[4][s] = fmaf(-2.0f, x4 - off, e2);
        base_[5][s] = fmaf(-2.0f, x5 - off, e2);
    }

    // ---- row (GT) features: row = lane, every wave holds all 64 rows ----
    float g0r, g1r, g2r, g3r, g4r; int clsr;
    {
        const float* gp = tracks + ((size_t)b * N + lane) * 6;
        g0r = gp[0]; g1r = gp[1]; g2r = gp[2]; g3r = gp[3]; g4r = gp[4];
        clsr = (int)gp[5];
    }

    // ---- Phase B (parallel over waves): u_i = min_j c[i][j] + argmin ----
    for (int t = 0; t < N / 4; ++t) {
        const int i = (N / 4) * wid + t;
        float g0 = readlane_f(g0r, i), g1 = readlane_f(g1r, i),
              g2 = readlane_f(g2r, i), g3 = readlane_f(g3r, i),
              g4 = readlane_f(g4r, i);
        int cls = readlane_i(clsr, i);
        float msk[SLOTS];
        #pragma unroll
        for (int s = 0; s < SLOTS; ++s) {
            const bool slotvalid = (s < SLOTS - 1) || s4ok;
            float t01 = (cls == 1) ? base_[1][s] : base_[0][s];
            float t23 = (cls == 3) ? base_[3][s] : base_[2][s];
            float t45 = (cls == 5) ? base_[5][s] : base_[4][s];
            float t03 = (cls >= 2) ? t23 : t01;
            float bb  = (cls >= 4) ? t45 : t03;
            float cc = fabsf(co0[s] - g0) + fabsf(co1[s] - g1)
                     + fabsf(co2[s] - g2) + fabsf(co3[s] - g3);
            float cost = fmaf(5.0f, cc, fmaf(2.0f, fabsf(wi_[s] - g4), bb));
            msk[s] = slotvalid ? cost : INF;
        }
        float lbest = fminf(fminf(fminf(msk[0], msk[1]), fminf(msk[2], msk[3])), msk[4]);
        unsigned jc = 0x7fffffffu;
        #pragma unroll
        for (int s = SLOTS - 1; s >= 0; --s)
            if (msk[s] == lbest) jc = (unsigned)(lane + 64 * s);
        float gmin = wave_min(lbest);
        unsigned long long ball = __ballot(lbest == gmin);
        int winner = __ffsll(ball) - 1;
        int bj = readlane_i((int)jc, winner);
        if (lane == 0) { s_u[i] = gmin; s_want[i] = bj; }
    }
    __syncthreads();
    if (wid != 0) return;   // last barrier passed; wave 0 continues alone

    // ================= wave 0 only from here =================
    float u_r = s_u[lane];
    int want_ = s_want[lane];

    // ---- conflict resolution: lowest row wins its argmin column ----
    #pragma unroll
    for (int s = 0; s < SLOTS; ++s) s_colowner[lane + 64 * s] = 0x7fffffff;
    __threadfence_block();   // intra-wave LDS ordering
    atomicMin(&s_colowner[want_], lane);
    __threadfence_block();
    int col4row_r = (s_colowner[want_] == lane) ? want_ : -1;

    float v_[SLOTS];
    #pragma unroll
    for (int s = 0; s < SLOTS; ++s) v_[s] = 0.0f;

    // ---- Phase C0: serial JV augmenting row reduction (fused min2) ----
    {
        unsigned long long freeball = __ballot(col4row_r == -1);
        int arr_iters = 0;
        while (freeball && arr_iters < 4 * N) {
            ++arr_iters;
            const int i = __ffsll(freeball) - 1;
            freeball &= (freeball - 1);

            float g0 = readlane_f(g0r, i), g1 = readlane_f(g1r, i),
                  g2 = readlane_f(g2r, i), g3 = readlane_f(g3r, i),
                  g4 = readlane_f(g4r, i);
            int cls = readlane_i(clsr, i);

            // per-lane min (m1,j1) and second-min (m2) of reduced cost c - v
            float m1 = INF, m2 = INF;
            unsigned j1 = 0x7fffffffu;
            #pragma unroll
            for (int s = 0; s < SLOTS; ++s) {
                const bool slotvalid = (s < SLOTS - 1) || s4ok;
                float t01 = (cls == 1) ? base_[1][s] : base_[0][s];
                float t23 = (cls == 3) ? base_[3][s] : base_[2][s];
                float t45 = (cls == 5) ? base_[5][s] : base_[4][s];
                float t03 = (cls >= 2) ? t23 : t01;
                float bb  = (cls >= 4) ? t45 : t03;
                float cc = fabsf(co0[s] - g0) + fabsf(co1[s] - g1)
                         + fabsf(co2[s] - g2) + fabsf(co3[s] - g3);
                float cost = fmaf(5.0f, cc, fmaf(2.0f, fabsf(wi_[s] - g4), bb));
                float r = slotvalid ? (cost - v_[s]) : INF;
                if (r < m1)      { m2 = m1; m1 = r; j1 = (unsigned)(lane + 64 * s); }
                else if (r < m2) { m2 = r; }
            }
            // single fused chain: global (u1, u2)
            float u1, u2;
            wave_min2(m1, m2, u1, u2);
            unsigned long long ball = __ballot(m1 == u1);
            int winner = __ffsll(ball) - 1;
            int bj = readlane_i((int)j1, winner);

            // duals: u[i] = u2; v[bj] -= (u2 - u1)
            if (lane == i) u_r = u2;
            const float dv = u2 - u1;
            const int bl = bj & 63, bs = bj >> 6;
            if (dv > 0.0f) {
                #pragma unroll
                for (int s = 0; s < SLOTS; ++s)
                    if (bs == s && lane == bl) v_[s] -= dv;
            }
            // displace current owner of bj (if any), assign i -> bj
            unsigned long long ball2 = __ballot(col4row_r == bj);
            if (lane == i) col4row_r = bj;
            if (ball2) {
                int k = __ffsll(ball2) - 1;
                if (lane == k) col4row_r = -1;
                freeball |= (1ull << k);
            }
        }
    }

    // ---- Phase C1: shortest augmenting path for any cap leftovers ----
    float shortest_[SLOTS];
    int path_[SLOTS];
    bool SC_[SLOTS];

    unsigned long long freeball = __ballot(col4row_r == -1);
    while (freeball) {
        const int cur = __ffsll(freeball) - 1;
        freeball &= (freeball - 1);

        #pragma unroll
        for (int s = 0; s < SLOTS; ++s) {
            shortest_[s] = INF;
            SC_[s] = (s == SLOTS - 1) ? !s4ok : false;
        }
        bool SRr = false;
        float minv = 0.0f;
        int i = cur;
        int sink;

        for (;;) {
            SRr = SRr || (lane == i);
            float g0 = readlane_f(g0r, i), g1 = readlane_f(g1r, i),
                  g2 = readlane_f(g2r, i), g3 = readlane_f(g3r, i),
                  g4 = readlane_f(g4r, i);
            int   cls = readlane_i(clsr, i);
            float muv = minv - readlane_f(u_r, i);

            float bb[SLOTS];
            #pragma unroll
            for (int s = 0; s < SLOTS; ++s) {
                float t01 = (cls == 1) ? base_[1][s] : base_[0][s];
                float t23 = (cls == 3) ? base_[3][s] : base_[2][s];
                float t45 = (cls == 5) ? base_[5][s] : base_[4][s];
                float t03 = (cls >= 2) ? t23 : t01;
                bb[s] = (cls >= 4) ? t45 : t03;
            }
            float msk[SLOTS];
            #pragma unroll
            for (int s = 0; s < SLOTS; ++s) {
                if (!SC_[s]) {
                    float cc = fabsf(co0[s] - g0) + fabsf(co1[s] - g1)
                             + fabsf(co2[s] - g2) + fabsf(co3[s] - g3);
                    float cost = fmaf(5.0f, cc, fmaf(2.0f, fabsf(wi_[s] - g4), bb[s]));
                    float d = muv + cost - v_[s];
                    if (d < shortest_[s]) { shortest_[s] = d; path_[s] = i; }
                    msk[s] = shortest_[s];
                } else {
                    msk[s] = INF;
                }
            }
            float lbest = fminf(fminf(fminf(msk[0], msk[1]), fminf(msk[2], msk[3])), msk[4]);
            unsigned jc = 0x7fffffffu;
            #pragma unroll
            for (int s = SLOTS - 1; s >= 0; --s)
                if (msk[s] == lbest) jc = (unsigned)(lane + 64 * s);
            float gmin = wave_min(lbest);
            unsigned long long ball = __ballot(lbest == gmin);
            int winner = __ffsll(ball) - 1;
            int bj = readlane_i((int)jc, winner);
            minv = gmin;

            const int bl = bj & 63, bs = bj >> 6;
            #pragma unroll
            for (int s = 0; s < SLOTS; ++s)
                if (bs == s && lane == bl) SC_[s] = true;
            unsigned long long ball2 = __ballot(col4row_r == bj);
            if (ball2 == 0ull) { sink = bj; break; }
            i = __ffsll(ball2) - 1;
        }

        const float minval = minv;
        {
            int c = col4row_r;
            int cl = c & 63, cs = c >> 6;
            float t0 = __shfl(shortest_[0], cl), t1 = __shfl(shortest_[1], cl),
                  t2 = __shfl(shortest_[2], cl), t3 = __shfl(shortest_[3], cl),
                  t4 = __shfl(shortest_[4], cl);
            float shc = t0;
            shc = (cs == 1) ? t1 : shc;
            shc = (cs == 2) ? t2 : shc;
            shc = (cs == 3) ? t3 : shc;
            shc = (cs == 4) ? t4 : shc;
            if (lane == cur) u_r += minval;
            else if (SRr)    u_r += minval - shc;
        }
        #pragma unroll
        for (int s = 0; s < SLOTS; ++s) {
            const bool slotvalid = (s < SLOTS - 1) || s4ok;
            if (slotvalid && SC_[s]) v_[s] -= minval - shortest_[s];
        }
        int j = sink;
        for (;;) {
            const int jl = j & 63, js = j >> 6;
            int ii_sel = path_[0];
            ii_sel = (js == 1) ? path_[1] : ii_sel;
            ii_sel = (js == 2) ? path_[2] : ii_sel;
            ii_sel = (js == 3) ? path_[3] : ii_sel;
            ii_sel = (js == 4) ? path_[4] : ii_sel;
            int ii = readlane_i(ii_sel, jl);
            int t = readlane_i(col4row_r, ii);
            if (lane == ii) col4row_r = j;
            j = t;
            if (ii == cur) break;
        }
    }

    // ---- matched-column bitmap for the noobj term (wave-0 internal) ----
    #pragma unroll
    for (int s = 0; s < SLOTS; ++s) s_matched[lane + 64 * s] = 0;
    __threadfence_block();
    s_matched[col4row_r] = 1;     // every row matched; col4row_r in [0,Q)
    __threadfence_block();

    // ---- per-batch loss partials ----
    float pc, pw, pef, pex;
    {
        const int p = col4row_r;          // pred matched to row=lane (per-lane)
        const int pl = p & 63, ps = p >> 6;
        #define GATH(dst, a0, a1, a2, a3, a4)                                   \
        {   float t0 = __shfl(a0, pl), t1 = __shfl(a1, pl), t2 = __shfl(a2, pl),\
                  t3 = __shfl(a3, pl), t4 = __shfl(a4, pl);                     \
            dst = t0;                                                           \
            dst = (ps == 1) ? t1 : dst;                                         \
            dst = (ps == 2) ? t2 : dst;                                         \
            dst = (ps == 3) ? t3 : dst;                                         \
            dst = (ps == 4) ? t4 : dst; }
        float mc0, mc1, mc2, mc3, mw, mpe, me2;
        GATH(mc0, co0[0], co0[1], co0[2], co0[3], co0[4])
        GATH(mc1, co1[0], co1[1], co1[2], co1[3], co1[4])
        GATH(mc2, co2[0], co2[1], co2[2], co2[3], co2[4])
        GATH(mc3, co3[0], co3[1], co3[2], co3[3], co3[4])
        GATH(mw,  wi_[0], wi_[1], wi_[2], wi_[3], wi_[4])
        GATH(mpe, pe_[0], pe_[1], pe_[2], pe_[3], pe_[4])
        GATH(me2, ec2_[0], ec2_[1], ec2_[2], ec2_[3], ec2_[4])
        float b0, b1, b2, b3, b4, b5;
        GATH(b0, base_[0][0], base_[0][1], base_[0][2], base_[0][3], base_[0][4])
        GATH(b1, base_[1][0], base_[1][1], base_[1][2], base_[1][3], base_[1][4])
        GATH(b2, base_[2][0], base_[2][1], base_[2][2], base_[2][3], base_[2][4])
        GATH(b3, base_[3][0], base_[3][1], base_[3][2], base_[3][3], base_[3][4])
        GATH(b4, base_[4][0], base_[4][1], base_[4][2], base_[4][3], base_[4][4])
        GATH(b5, base_[5][0], base_[5][1], base_[5][2], base_[5][3], base_[5][4])
        #undef GATH
        float mb = b0;
        mb = (clsr == 1) ? b1 : mb;
        mb = (clsr == 2) ? b2 : mb;
        mb = (clsr == 3) ? b3 : mb;
        mb = (clsr == 4) ? b4 : mb;
        mb = (clsr == 5) ? b5 : mb;
        pc = fabsf(mc0 - g0r) + fabsf(mc1 - g1r) + fabsf(mc2 - g2r) + fabsf(mc3 - g3r);
        pw = fabsf(mw - g4r);
        pef = (mb - me2) * 0.5f;          // = -log_softmax[cls] (recovered from base)
        pex = -logf(mpe);
    }
    float pno = 0.0f;
    #pragma unroll
    for (int s = 0; s < SLOTS; ++s) {
        const bool slotvalid = (s < SLOTS - 1) || s4ok;
        if (slotvalid && !s_matched[lane + 64 * s]) pno -= logf(1.0f - pe_[s]);
    }

    // ---- wave reduce 5 partials; publish; last block finalizes ----
    float vals[5] = {pc, pw, pef, pex, pno};
    #pragma unroll
    for (int k = 0; k < 5; ++k) {
        float x = vals[k];
        #pragma unroll
        for (int off = 1; off < 64; off <<= 1) x += __shfl_xor(x, off);
        vals[k] = x;
    }
    if (lane == 0) {
        #pragma unroll
        for (int k = 0; k < 5; ++k) atomicExch(&part[b * 5 + k], vals[k]);
    }
    __threadfence();
    unsigned int done = 0;
    if (lane == 0) done = atomicAdd(counter, 1u);
    done = __shfl(done, 0);
    if (done == BATCH - 1) {
        __threadfence();
        float s0 = atomicAdd(&part[lane * 5 + 0], 0.0f);
        float s1 = atomicAdd(&part[lane * 5 + 1], 0.0f);
        float s2 = atomicAdd(&part[lane * 5 + 2], 0.0f);
        float s3 = atomicAdd(&part[lane * 5 + 3], 0.0f);
        float s4 = atomicAdd(&part[lane * 5 + 4], 0.0f);
        #pragma unroll
        for (int off = 1; off < 64; off <<= 1) {
            s0 += __shfl_xor(s0, off);
            s1 += __shfl_xor(s1, off);
            s2 += __shfl_xor(s2, off);
            s3 += __shfl_xor(s3, off);
            s4 += __shfl_xor(s4, off);
        }
        if (lane == 0) {
            const float n_matched = 4096.0f;     // B*N (mask all-ones)
            const float n_unmatched = 15104.0f;  // B*Q - B*N
            float coord = 5.0f * s0 / n_matched;
            float wloss = 2.0f * s1 / n_matched;
            float efl   = 2.0f * s2 / n_matched;
            float exl   = 2.0f * s3 / n_matched;
            float nol   = 1.0f * s4 / n_unmatched;
            out[0] = coord + wloss + efl + exl + nol;
            out[1] = coord;
            out[2] = wloss;
            out[3] = efl;
            out[4] = exl;
            out[5] = nol;
        }
    }
}

extern "C" void kernel_launch(void* const* d_in, const int* in_sizes, int n_in,
                              void* d_out, int out_size, void* d_ws, size_t ws_size,
                              hipStream_t stream) {
    const float* exists = (const float*)d_in[0];  // (64,300,1)
    const float* coords = (const float*)d_in[1];  // (64,300,4)
    const float* width  = (const float*)d_in[2];  // (64,300,1)
    const float* ef     = (const float*)d_in[3];  // (64,300,6)
    const float* tracks = (const float*)d_in[4];  // (64,64,6)
    // d_in[5] = track_mask: all ones by construction, unused

    float* part = (float*)d_ws;                                   // 64*5 floats
    unsigned int* counter = (unsigned int*)((char*)d_ws + BATCH * 5 * sizeof(float));
    (void)hipMemsetAsync(counter, 0, sizeof(unsigned int), stream);  // capture-legal

    hml_fused_kernel<<<BATCH, NT, 0, stream>>>(exists, coords, width, ef, tracks,
                                               part, counter, (float*)d_out);
}